// Round 8
// baseline (376.789 us; speedup 1.0000x reference)
//
#include <hip/hip_runtime.h>
#include <cstdint>
#include <cstddef>

#define N_NODES 100000
#define D 128
#define R 4
#define NE 150000
#define LAYERS 2
#define NROWS (R * N_NODES)   // 400000
#define CAP 16                // max in-degree per (rel,dst); Poisson(1.5) -> P(>16) ~ 1e-12
#define OVFS 12               // overflow slots per row (CAP - 4 inline)
#define TILES (N_NODES / 16)  // 6250
#define AGG_BLOCKS ((R * TILES) / 8)   // 3125 blocks x 8 waves = 25000 waves
#define GEMM_BLOCKS 1024

typedef __attribute__((ext_vector_type(8))) short bf16x8;
typedef __attribute__((ext_vector_type(4))) float f32x4;
typedef __attribute__((ext_vector_type(4))) int i32x4;
typedef __attribute__((ext_vector_type(4))) unsigned short u16x4;

__device__ __forceinline__ unsigned short f2bf(float x) {
  union { float f; unsigned int u; } v; v.f = x;
  unsigned int u = v.u;
  return (unsigned short)((u + 0x7fffu + ((u >> 16) & 1u)) >> 16);  // RNE
}
__device__ __forceinline__ float bf2f(unsigned short u) {
  union { unsigned int i; float f; } v; v.i = ((unsigned int)u) << 16;
  return v.f;
}

// ---- prep1: out-degree count + emb fp32->bf16 + Wt transpose + bmean ------
__global__ void prep1_kernel(const float* __restrict__ emb, const float* __restrict__ W,
                             const float* __restrict__ biases, const int* __restrict__ edges,
                             int* __restrict__ deg_i, unsigned short* __restrict__ hb,
                             unsigned short* __restrict__ Wt, float* __restrict__ bmean) {
  int t = blockIdx.x * blockDim.x + threadIdx.x;
  if (t < N_NODES * D / 4) {
    f32x4 v = *(const f32x4*)(emb + (size_t)t * 4);
    u16x4 o;
#pragma unroll
    for (int j = 0; j < 4; ++j) o[j] = f2bf(v[j]);
    *(u16x4*)(hb + (size_t)t * 4) = o;
  }
  if (t < NE * R) {
    int r = t / NE;
    int e = t - r * NE;
    int src = edges[(size_t)(r * 2) * NE + e];
    atomicAdd(&deg_i[r * N_NODES + src], 1);
  }
  if (t < LAYERS * R * D * D) {
    int k = t & 127;
    int c = (t >> 7) & 127;
    int lr = t >> 14;
    Wt[((size_t)lr << 14) | (c << 7) | k] = f2bf(W[((size_t)lr << 14) | (k << 7) | c]);
  }
  if (t < LAYERS * D) {
    int l = t >> 7, cc = t & 127;
    float s = 0.f;
    for (int r = 0; r < R; ++r) s += biases[((size_t)l * R + r) * D + cc];
    bmean[t] = s * 0.25f;
  }
}

// fill padded edge records {src, rsqrt(deg_out[src])}; cursor counts in-degree.
// SoA: slots 0..3 packed per (rel,tile): rec2[r][tile][m][slot]; 4..15 -> ovf.
// Neither zeroed: aggregate kernel masks by cnt.
__global__ void fill_kernel(const int* __restrict__ edges, const int* __restrict__ deg_i,
                            int* __restrict__ cursor, int2* __restrict__ rec2,
                            int2* __restrict__ ovf) {
  int e = blockIdx.x * blockDim.x + threadIdx.x;
  int r = blockIdx.y;
  if (e >= NE) return;
  int src = edges[(size_t)(r * 2) * NE + e];
  int dst = edges[(size_t)(r * 2 + 1) * NE + e];
  float sc = rsqrtf(fmaxf((float)deg_i[r * N_NODES + src], 1.0f));
  int rowg = r * N_NODES + dst;
  int slot = atomicAdd(&cursor[rowg], 1);
  if (slot < 4) {
    rec2[(((size_t)(r * TILES + (dst >> 4)) * 16 + (dst & 15)) << 2) + slot] =
        make_int2(src, __float_as_int(sc));
  } else if (slot < CAP) {
    ovf[(size_t)rowg * OVFS + (slot - 4)] = make_int2(src, __float_as_int(sc));
  }
}

// ======== K1: barrier-free gather/aggregate ================================
// 25000 fully-independent waves (one per (rel,tile)), 16 gathering waves/CU
// (vs 4 in the coupled producer/consumer kernel) -> 4x gather concurrency,
// and no barrier ever drains the memory pipe. Body = the proven R7 producer
// (104 VGPR, no scratch). Output layout = flat MFMA-fragment order
// agg[rel][tile][ks][lane][8]: stores AND the GEMM's loads are perfectly
// coalesced 1KB-per-instruction. rsqrt(in-degree) folded into the bf16 rows
// (row scaling commutes with the GEMM).
__global__ __launch_bounds__(512, 4) void agg_kernel(
    const unsigned short* __restrict__ hin,    // [N][128] bf16
    const int2* __restrict__ rec2,             // [R][TILES][16][4] {src, s_out}
    const int2* __restrict__ ovf,              // [NROWS][OVFS]
    const int* __restrict__ cnt,               // [NROWS]
    unsigned short* __restrict__ agg) {        // [R][TILES][4][64][8] bf16
  const int gw = (blockIdx.x * blockDim.x + threadIdx.x) >> 6;   // 0..24999
  const int lane = threadIdx.x & 63;
  const int m = lane & 15;
  const int q = lane >> 4;
  const int rel = gw / TILES;
  const int tile = gw - rel * TILES;

  const int rowg = rel * N_NODES + tile * 16 + m;
  const int2* rp = rec2 + (((size_t)gw * 16 + m) << 2);
  int cn = cnt[rowg];
  int n = cn > CAP ? CAP : cn;
  float sin_ = rsqrtf(fmaxf((float)cn, 1.0f));
  i32x4 r01 = *(const i32x4*)(rp);
  i32x4 r23 = *(const i32x4*)(rp + 2);
  int   srcs[4] = { r01.x, r01.z, r23.x, r23.z };
  float scs[4]  = { __int_as_float(r01.y), __int_as_float(r01.w),
                    __int_as_float(r23.y), __int_as_float(r23.w) };
#pragma unroll
  for (int e = 0; e < 4; ++e) {
    if (e >= n) { srcs[e] = 0; scs[e] = 0.f; }   // pads are garbage: mask; row 0 stays hot
  }
  float accf[4][8];
#pragma unroll
  for (int ks = 0; ks < 4; ++ks)
#pragma unroll
    for (int j = 0; j < 8; ++j) accf[ks][j] = 0.f;
#pragma unroll
  for (int e = 0; e < 4; ++e) {
    const unsigned short* hp = hin + (size_t)srcs[e] * D + q * 8;
#pragma unroll
    for (int ks = 0; ks < 4; ++ks) {
      bf16x8 a = *(const bf16x8*)(hp + ks * 32);
#pragma unroll
      for (int j = 0; j < 8; ++j)
        accf[ks][j] += scs[e] * bf2f((unsigned short)a[j]);
    }
  }
  if (__builtin_expect(n > 4, 0)) {   // rare tail (~1.4% of rows)
    const int2* op = ovf + (size_t)rowg * OVFS;
    for (int i = 4; i < n; i += 2) {
      i32x4 rr = *(const i32x4*)(op + (i - 4));
      bool pairOk = (i + 1) < n;
      int  sA = rr.x;
      int  sB = pairOk ? rr.z : 0;
      float c0 = __int_as_float(rr.y);
      float c1 = pairOk ? __int_as_float(rr.w) : 0.f;
      const unsigned short* h0 = hin + (size_t)sA * D + q * 8;
      const unsigned short* h1 = hin + (size_t)sB * D + q * 8;
#pragma unroll
      for (int ks = 0; ks < 4; ++ks) {
        bf16x8 a0 = *(const bf16x8*)(h0 + ks * 32);
        bf16x8 a1 = *(const bf16x8*)(h1 + ks * 32);
#pragma unroll
        for (int j = 0; j < 8; ++j)
          accf[ks][j] += c0 * bf2f((unsigned short)a0[j]) + c1 * bf2f((unsigned short)a1[j]);
      }
    }
  }
  unsigned short* dstp = agg + (((size_t)gw * 4) * 64 + lane) * 8;
#pragma unroll
  for (int ks = 0; ks < 4; ++ks) {
    union { bf16x8 v; unsigned short s[8]; } u;
#pragma unroll
    for (int j = 0; j < 8; ++j) u.s[j] = f2bf(accf[ks][j] * sin_);
    *(bf16x8*)(dstp + (size_t)ks * 64 * 8) = u.v;
  }
}

// ======== K2: barrier-free dense GEMM + epilogue ===========================
// Each wave = one col-quarter (32 cols) of a 16-row tile; 4 waves/block cover
// the tile; grid-strides over tiles so breg (the proven R7 consumer fragment
// set) is loaded once. A streams contiguously from agg (fragment order).
// s_in already folded -> all 16 MFMAs accumulate into one f32x4 per col-tile.
__global__ __launch_bounds__(256, 2) void gemm_kernel(
    const unsigned short* __restrict__ agg,    // [R][TILES][4][64][8] bf16
    const unsigned short* __restrict__ Wt,     // layer: [R][128 col][128 k] bf16
    const float* __restrict__ bmean,           // [128]
    const unsigned short* __restrict__ resid_bf,
    float* __restrict__ out_f,
    unsigned short* __restrict__ out_bf) {
  const int w = threadIdx.x >> 6;      // col-quarter 0..3
  const int lane = threadIdx.x & 63;
  const int m = lane & 15;
  const int q = lane >> 4;

  bf16x8 breg[R][4][2];
#pragma unroll
  for (int r = 0; r < R; ++r) {
    const unsigned short* wr = Wt + ((size_t)r << 14);
#pragma unroll
    for (int ks = 0; ks < 4; ++ks)
#pragma unroll
      for (int c = 0; c < 2; ++c) {
        int ct = w * 2 + c;
        breg[r][ks][c] = *(const bf16x8*)(wr + ((ct * 16 + m) << 7) + ks * 32 + q * 8);
      }
  }

  for (int tile = blockIdx.x; tile < TILES; tile += GEMM_BLOCKS) {
    f32x4 acc[2];
#pragma unroll
    for (int c = 0; c < 2; ++c) acc[c] = (f32x4){0.f, 0.f, 0.f, 0.f};
#pragma unroll
    for (int r = 0; r < R; ++r) {
      const unsigned short* ap =
          agg + ((size_t)(r * TILES + tile) * 256 + lane) * 8;   // 256 = 4 ks * 64 lanes
      bf16x8 a0 = *(const bf16x8*)(ap);
      bf16x8 a1 = *(const bf16x8*)(ap + 512);
      bf16x8 a2 = *(const bf16x8*)(ap + 1024);
      bf16x8 a3 = *(const bf16x8*)(ap + 1536);
#pragma unroll
      for (int c = 0; c < 2; ++c) {
        acc[c] = __builtin_amdgcn_mfma_f32_16x16x32_bf16(a0, breg[r][0][c], acc[c], 0, 0, 0);
        acc[c] = __builtin_amdgcn_mfma_f32_16x16x32_bf16(a1, breg[r][1][c], acc[c], 0, 0, 0);
        acc[c] = __builtin_amdgcn_mfma_f32_16x16x32_bf16(a2, breg[r][2][c], acc[c], 0, 0, 0);
        acc[c] = __builtin_amdgcn_mfma_f32_16x16x32_bf16(a3, breg[r][3][c], acc[c], 0, 0, 0);
      }
    }
#pragma unroll
    for (int c = 0; c < 2; ++c) {
      int colx = (w * 2 + c) * 16 + m;
      float bm = bmean[colx];
#pragma unroll
      for (int i = 0; i < 4; ++i) {
        int row = tile * 16 + q * 4 + i;
        float v = acc[c][i] * 0.25f + bm;
        v = (v >= 0.f) ? v : 0.2f * v;
        if (resid_bf) v += bf2f(resid_bf[(size_t)row * D + colx]);
        if (out_f) out_f[(size_t)row * D + colx] = v;
        else       out_bf[(size_t)row * D + colx] = f2bf(v);
      }
    }
  }
}

extern "C" void kernel_launch(void* const* d_in, const int* in_sizes, int n_in,
                              void* d_out, int out_size, void* d_ws, size_t ws_size,
                              hipStream_t stream) {
  const float* emb    = (const float*)d_in[0];
  const float* W      = (const float*)d_in[1];
  const float* biases = (const float*)d_in[2];
  const int*   edges  = (const int*)d_in[3];
  float* out = (float*)d_out;
  char* ws = (char*)d_ws;

  size_t off = 0;
  auto alloc = [&](size_t bytes) { size_t o = off; off += (bytes + 255) & ~255ull; return o; };
  // only the int arrays (deg_i | cursor) need zeroing -> 3.2 MB memset
  int* ints      = (int*)(ws + alloc((size_t)2 * NROWS * 4));   // [deg_i | cursor]
  int* deg_i     = ints;
  int* cursor    = ints + NROWS;
  size_t zero_bytes = off;
  int2* rec2     = (int2*)(ws + alloc((size_t)R * TILES * 16 * 4 * 8));  // 12.8 MB, NOT zeroed
  int2* ovf      = (int2*)(ws + alloc((size_t)NROWS * OVFS * 8));        // 38.4 MB, NOT zeroed
  unsigned short* hb  = (unsigned short*)(ws + alloc((size_t)N_NODES * D * 2));
  unsigned short* hb2 = (unsigned short*)(ws + alloc((size_t)N_NODES * D * 2));
  unsigned short* Wt  = (unsigned short*)(ws + alloc((size_t)LAYERS * R * D * D * 2));
  float* bmean   = (float*)(ws + alloc((size_t)LAYERS * D * 4));
  unsigned short* agg = (unsigned short*)(ws + alloc((size_t)R * N_NODES * D * 2));  // 102.4 MB
  (void)ws_size;

  // ---- prep: memset -> prep1(count+conversions) -> fill ----
  hipMemsetAsync(ws, 0, zero_bytes, stream);
  prep1_kernel<<<(N_NODES * D / 4 + 255) / 256, 256, 0, stream>>>(
      emb, W, biases, edges, deg_i, hb, Wt, bmean);
  fill_kernel<<<dim3((NE + 255) / 256, R), 256, 0, stream>>>(edges, deg_i, cursor, rec2, ovf);

  // layer 0: aggregate(hb) -> agg; GEMM(agg) -> hb2 (bf16), no residual
  agg_kernel<<<AGG_BLOCKS, 512, 0, stream>>>(hb, rec2, ovf, cursor, agg);
  gemm_kernel<<<GEMM_BLOCKS, 256, 0, stream>>>(agg, Wt, bmean, nullptr, nullptr, hb2);
  // layer 1: aggregate(hb2) -> agg; GEMM(agg) -> out (fp32), residual = hb2
  agg_kernel<<<AGG_BLOCKS, 512, 0, stream>>>(hb2, rec2, ovf, cursor, agg);
  gemm_kernel<<<GEMM_BLOCKS, 256, 0, stream>>>(agg, Wt + (size_t)R * D * D, bmean + D,
                                               hb2, out, nullptr);
}